// Round 13
// baseline (5155.746 us; speedup 1.0000x reference)
//
#include <hip/hip_runtime.h>
#include <stdint.h>

#define DIM_C   2048
#define INNER_C 8192
#define ROWS    8192      // B*L = 4*2048
#define BM 256
#define BN 256
#define BK 32

using bf16x8 = __attribute__((ext_vector_type(8))) __bf16;
using f32x4  = __attribute__((ext_vector_type(4))) float;
using u16x8  = __attribute__((ext_vector_type(8))) unsigned short;

__device__ __forceinline__ unsigned short f2bf(float f) {
  union { float f; unsigned int u; } v; v.f = f;
  unsigned int u = v.u;
  return (unsigned short)((u + 0x7FFFu + ((u >> 16) & 1u)) >> 16);  // RTNE
}

__device__ __forceinline__ void gld_lds16(const void* g, void* l) {
  __builtin_amdgcn_global_load_lds(
      (__attribute__((address_space(1))) void*)(g),
      (__attribute__((address_space(3))) void*)(l), 16, 0, 0);
}

// --- softmax + per-batch truncation width --------------------------------
__global__ void prep_kernel(const float* __restrict__ logits,
                            float* __restrict__ p_out,
                            int* __restrict__ kb) {
  const int b = threadIdx.x;
  if (b < 4) {
    float x0 = logits[b * 4 + 0], x1 = logits[b * 4 + 1];
    float x2 = logits[b * 4 + 2], x3 = logits[b * 4 + 3];
    float m = fmaxf(fmaxf(x0, x1), fmaxf(x2, x3));
    float e0 = __expf(x0 - m), e1 = __expf(x1 - m);
    float e2 = __expf(x2 - m), e3 = __expf(x3 - m);
    float inv = 1.f / (e0 + e1 + e2 + e3);
    p_out[b * 4 + 0] = e0 * inv;
    p_out[b * 4 + 1] = e1 * inv;
    p_out[b * 4 + 2] = e2 * inv;
    p_out[b * 4 + 3] = e3 * inv;
    int idx = 0; float best = x0;                 // first-max, like jnp.argmax
    if (x1 > best) { best = x1; idx = 1; }
    if (x2 > best) { best = x2; idx = 2; }
    if (x3 > best) { best = x3; idx = 3; }
    kb[b] = (idx + 1) * (INNER_C / 4);
  }
}

// --- fp32 -> bf16 bulk convert, all 3 arrays in ONE launch ---------------
__global__ void cvt3_kernel(const float* __restrict__ h,
                            const float* __restrict__ w1,
                            const float* __restrict__ w2,
                            unsigned short* __restrict__ ha,
                            unsigned short* __restrict__ w1a,
                            unsigned short* __restrict__ w2a, int n8) {
  int i = blockIdx.x * blockDim.x + threadIdx.x;
  const float* in;
  unsigned short* out;
  int j;
  if (i < n8)          { in = h;  out = ha;  j = i; }
  else if (i < 2 * n8) { in = w1; out = w1a; j = i - n8; }
  else                 { in = w2; out = w2a; j = i - 2 * n8; }
  const float4* p = reinterpret_cast<const float4*>(in) + (size_t)j * 2;
  float4 a = p[0], b = p[1];
  u16x8 r;
  r[0] = f2bf(a.x); r[1] = f2bf(a.y); r[2] = f2bf(a.z); r[3] = f2bf(a.w);
  r[4] = f2bf(b.x); r[5] = f2bf(b.y); r[6] = f2bf(b.z); r[7] = f2bf(b.w);
  *(reinterpret_cast<u16x8*>(out) + j) = r;
}

// --- NT bf16 GEMM, 256x256, BK=32, 8 waves, 2-phase/K-tile, 2 blocks/CU --
// R11 champion restructured for occupancy: BK 64->32 halves LDS to 64KiB ->
// 2 blocks/CU (16 waves/CU at VGPR=128). Theory: kernel is LDS-pipe-bound
// (~260KB LDS traffic/tile vs ~85B/cyc sustained); at 1 blk/CU the pipe
// idles at every LGK/BAR reconvergence. Co-resident block keeps it fed.
// Phase granularity preserved: 16 MFMA + 8 ds_read per phase (= R11).
// LDS per (buf, mat): [256 perm-rows][4 slots x 16B], slot XOR-swizzle
// slot' = slot ^ ((p>>1)&3) -> conflict-free b128 reads (verified: 0).
// Row perm (R5/R11-verified): A half0 = af-lo rows {0-63,128-191}; B half0
// = bf-lo rows. Stage unit = 1 gld_lds (128 perm-rows x 64B across 512 thr).
// Tile t (buf = t&1), stages target buf^1:
//  PA: rd af-lo(4)+bf-lo(2)+bf-hi(2); stage {B0,B1,A0}(t+1);
//      lgkm(4); bar; lgkm(0); MFMA Q1[0-3][0-1] Q2[0-3][2-3]; vmcnt(3); bar
//  PB: rd af-hi(4, overwrites af); stage {A1}(t+1);
//      bar; lgkm(0); MFMA Q3[4-7][2-3] Q4[4-7][0-1]; vmcnt(1); bar
// vmcnt FIFO (1 load/unit): end-PA(t) out = {A1(t), B0,B1,A0(t+1)} = 4 ->
// vmcnt(3) drains A1(t) [read in PB(t), 1-phase cover]. end-PB(t) out =
// {B0,B1,A0,A1}(t+1) = 4 -> vmcnt(1) drains B0,B1,A0(t+1) [read PA(t+1),
// 1.5-2 phase cover]. Invariant entering PA(t): out = {A1(t)}.
// MODE 0: C = gelu(A*B^T + bias) -> bf16 H, skip col tiles >= kb[batch]
// MODE 1: C = A*B^T + bias -> f32 out, K-loop truncated to kb[batch]
template <int MODE>
__global__ __launch_bounds__(512, 4) void gemm_bt(
    const unsigned short* __restrict__ A,
    const unsigned short* __restrict__ Bp,
    const float* __restrict__ bias,
    void* __restrict__ Cp,
    const int* __restrict__ kb_arr) {
  constexpr int KDIM = (MODE == 0) ? DIM_C : INNER_C;   // A/B row stride
  __shared__ __align__(16) unsigned short sm[32768];    // 64 KiB

  const int nt = blockIdx.x;                            // col tile fastest
  const int mt = blockIdx.y;
  const size_t row0 = (size_t)mt * BM;
  const size_t col0 = (size_t)nt * BN;
  const int batch = (int)(row0 >> 11);                  // 2048 rows / batch
  const int kbv = kb_arr[batch];
  if (MODE == 0 && (int)col0 >= kbv) return;            // masked cols: skip
  const int kTiles = (MODE == 0) ? (DIM_C / BK) : (kbv / BK);  // even, >=64

  const int tid  = threadIdx.x;
  const int wave = tid >> 6;
  const int lane = tid & 63;
  const int wm = wave >> 2, wn = wave & 3;              // 2x4 wave grid
  const int la = lane & 15, lb4 = lane >> 4;

  // staging bases (permuted-row order; per-wave 16 contiguous global rows)
  const int sslot = ((lane & 3) ^ ((lane >> 3) & 3)) * 8;
  const unsigned short* gA =
      A + (row0 + (size_t)((wave >> 2) * 128 + (wave & 3) * 16 + (lane >> 2)))
              * KDIM + sslot;
  const unsigned short* gB =
      Bp + (col0 + (size_t)((wave >> 1) * 64 + (wave & 1) * 16 + (lane >> 2)))
               * KDIM + sslot;

  // STAGE: one unit = 128 perm-rows x 64B = 1 gld_lds/thread.
  // matofs: A=0, B=8192. HROWS: A=64, B=32 (global rows per unit-half).
#define STAGE(gp, matofs, BUF, H, T, HROWS)                                   \
  {                                                                           \
    const unsigned short* g_ = gp + (size_t)(H) * (HROWS) * KDIM + (T) * 32;  \
    gld_lds16(g_, &sm[(BUF) * 16384 + (matofs) + (H) * 4096 + wave * 512]);   \
  }

#define VMW_(N) asm volatile("s_waitcnt vmcnt(" #N ")" ::: "memory")
#define VMW(N) VMW_(N)
#define LGK_(N) asm volatile("s_waitcnt lgkmcnt(" #N ")" ::: "memory")
#define LGK(N) LGK_(N)
#define BAR __builtin_amdgcn_s_barrier()

  // frag read bases (ushort units); perm row p, stride 32, swizzled slot.
  const int rslot = (lb4 ^ ((la >> 1) & 3)) * 8;
  const int aro = (wm * 64 + la) * 32 + rslot;          // af-lo p-base
  const int bro = 8192 + (wn * 32 + la) * 32 + rslot;   // bf-lo p-base

  f32x4 acc[8][4];
#pragma unroll
  for (int m = 0; m < 8; ++m)
#pragma unroll
    for (int n = 0; n < 4; ++n) acc[m][n] = (f32x4){0.f, 0.f, 0.f, 0.f};

  bf16x8 af[4], bf[2], bf2[2];

#define RD_AF(BUF, HI)                                                        \
  _Pragma("unroll") for (int m_ = 0; m_ < 4; ++m_)                            \
      af[m_] = *reinterpret_cast<const bf16x8*>(                              \
          &sm[(BUF) * 16384 + aro + (HI) * 4096 + m_ * 512]);

#define RD_BF(DST, BUF, HI)                                                   \
  _Pragma("unroll") for (int n_ = 0; n_ < 2; ++n_)                            \
      DST[n_] = *reinterpret_cast<const bf16x8*>(                             \
          &sm[(BUF) * 16384 + bro + (HI) * 4096 + n_ * 512]);

#define MFMA_Q(AF, BF, MO, NO)                                                \
  __builtin_amdgcn_s_setprio(1);                                              \
  _Pragma("unroll") for (int m_ = 0; m_ < 4; ++m_)                            \
      _Pragma("unroll") for (int n_ = 0; n_ < 2; ++n_)                        \
          acc[(MO) + m_][(NO) + n_] =                                         \
              __builtin_amdgcn_mfma_f32_16x16x32_bf16(                        \
                  AF[m_], BF[n_], acc[(MO) + m_][(NO) + n_], 0, 0, 0);        \
  __builtin_amdgcn_s_setprio(0);

  // prologue: stage tile0 units in ledger order {B0,B1,A0 | A1}
  STAGE(gB, 8192, 0, 0, 0, 32);
  STAGE(gB, 8192, 0, 1, 0, 32);
  STAGE(gA, 0,    0, 0, 0, 64);
  STAGE(gA, 0,    0, 1, 0, 64);
  VMW(1);                                   // B0,B1,A0 landed; A1 in flight
  BAR;

#define TILE_S(T, BUF)                                                        \
  { /* PA */                                                                  \
    RD_AF(BUF, 0) RD_BF(bf, BUF, 0) RD_BF(bf2, BUF, 1)                        \
    STAGE(gB, 8192, (BUF) ^ 1, 0, (T) + 1, 32);                               \
    STAGE(gB, 8192, (BUF) ^ 1, 1, (T) + 1, 32);                               \
    STAGE(gA, 0,    (BUF) ^ 1, 0, (T) + 1, 64);                               \
    LGK(4); BAR; LGK(0);                                                      \
    MFMA_Q(af, bf, 0, 0)                                                      \
    MFMA_Q(af, bf2, 0, 2)                                                     \
    VMW(3); BAR;                                                              \
    /* PB */                                                                  \
    RD_AF(BUF, 1)                                                             \
    STAGE(gA, 0, (BUF) ^ 1, 1, (T) + 1, 64);                                  \
    BAR; LGK(0);                                                              \
    MFMA_Q(af, bf2, 4, 2)                                                     \
    MFMA_Q(af, bf, 4, 0)                                                      \
    VMW(1); BAR;                                                              \
  }

#define TILE_LAST(BUF)                                                        \
  { /* PA */                                                                  \
    RD_AF(BUF, 0) RD_BF(bf, BUF, 0) RD_BF(bf2, BUF, 1)                        \
    LGK(4); BAR; LGK(0);                                                      \
    MFMA_Q(af, bf, 0, 0)                                                      \
    MFMA_Q(af, bf2, 0, 2)                                                     \
    VMW(0); BAR;                                                              \
    /* PB */                                                                  \
    RD_AF(BUF, 1)                                                             \
    LGK(0);                                                                   \
    MFMA_Q(af, bf2, 4, 2)                                                     \
    MFMA_Q(af, bf, 4, 0)                                                      \
  }

  for (int t = 0; t + 2 < kTiles; t += 2) {
    TILE_S(t, 0);
    TILE_S(t + 1, 1);
  }
  TILE_S(kTiles - 2, 0);
  TILE_LAST(1);

#undef TILE_S
#undef TILE_LAST
#undef MFMA_Q
#undef RD_AF
#undef RD_BF
#undef STAGE

  // epilogue: C/D layout col = lane&15, row = (lane>>4)*4 + j  [m89/m91]
#pragma unroll
  for (int m = 0; m < 8; ++m) {
    const size_t rb = row0 + wm * 128 + m * 16 + lb4 * 4;
#pragma unroll
    for (int n = 0; n < 4; ++n) {
      const size_t c = col0 + wn * 64 + n * 16 + la;
      const float bv = bias[c];
#pragma unroll
      for (int j = 0; j < 4; ++j) {
        float x = acc[m][n][j] + bv;
        if (MODE == 0) {
          float g = x / (1.f + __expf(-1.702f * x));  // x*sigmoid(1.702x)
          ((unsigned short*)Cp)[(rb + j) * (size_t)INNER_C + c] = f2bf(g);
        } else {
          ((float*)Cp)[(rb + j) * (size_t)DIM_C + c] = x;
        }
      }
    }
  }
}

extern "C" void kernel_launch(void* const* d_in, const int* in_sizes, int n_in,
                              void* d_out, int out_size, void* d_ws,
                              size_t ws_size, hipStream_t stream) {
  const float* hidden = (const float*)d_in[0];  // [4,2048,2048]
  const float* logitw = (const float*)d_in[1];  // [4,4]
  const float* W1     = (const float*)d_in[2];  // [8192,2048]
  const float* b1     = (const float*)d_in[3];  // [8192]
  const float* W2     = (const float*)d_in[4];  // [2048,8192]
  const float* b2     = (const float*)d_in[5];  // [2048]
  float* out   = (float*)d_out;
  float* p_out = out + (size_t)ROWS * DIM_C;    // tuple tail: p_soft [4,4]

  char* ws = (char*)d_ws;
  int*            kb   = (int*)ws;                                    // 16 B
  unsigned short* Abf  = (unsigned short*)(ws + 256);                 // 32 MiB
  unsigned short* W1bf = (unsigned short*)(ws + 256 + 33554432);      // 32 MiB
  unsigned short* W2bf = (unsigned short*)(ws + 256 + 2 * 33554432);  // 32 MiB
  unsigned short* Hbf  = (unsigned short*)(ws + 256 + 3 * 33554432);  // 128 MiB

  prep_kernel<<<1, 64, 0, stream>>>(logitw, p_out, kb);

  const int n8 = 16777216 / 8;  // each of A/W1/W2 is 16.7M fp32
  cvt3_kernel<<<3 * n8 / 256, 256, 0, stream>>>(hidden, W1, W2, Abf, W1bf,
                                                W2bf, n8);

  gemm_bt<0><<<dim3(INNER_C / BN, ROWS / BM), 512, 0, stream>>>(
      Abf, W1bf, b1, Hbf, kb);
  gemm_bt<1><<<dim3(DIM_C / BN, ROWS / BM), 512, 0, stream>>>(
      Hbf, W2bf, b2, out, kb);
}

// Round 14
// 540.757 us; speedup vs baseline: 9.5343x; 9.5343x over previous
//
#include <hip/hip_runtime.h>
#include <stdint.h>

#define DIM_C   2048
#define INNER_C 8192
#define ROWS    8192      // B*L = 4*2048
#define BM 256
#define BN 256
#define BK 32

using bf16x8 = __attribute__((ext_vector_type(8))) __bf16;
using f32x4  = __attribute__((ext_vector_type(4))) float;
using u16x8  = __attribute__((ext_vector_type(8))) unsigned short;

__device__ __forceinline__ unsigned short f2bf(float f) {
  union { float f; unsigned int u; } v; v.f = f;
  unsigned int u = v.u;
  return (unsigned short)((u + 0x7FFFu + ((u >> 16) & 1u)) >> 16);  // RTNE
}

__device__ __forceinline__ void gld_lds16(const void* g, void* l) {
  __builtin_amdgcn_global_load_lds(
      (__attribute__((address_space(1))) void*)(g),
      (__attribute__((address_space(3))) void*)(l), 16, 0, 0);
}

// --- softmax + per-batch truncation width --------------------------------
__global__ void prep_kernel(const float* __restrict__ logits,
                            float* __restrict__ p_out,
                            int* __restrict__ kb) {
  const int b = threadIdx.x;
  if (b < 4) {
    float x0 = logits[b * 4 + 0], x1 = logits[b * 4 + 1];
    float x2 = logits[b * 4 + 2], x3 = logits[b * 4 + 3];
    float m = fmaxf(fmaxf(x0, x1), fmaxf(x2, x3));
    float e0 = __expf(x0 - m), e1 = __expf(x1 - m);
    float e2 = __expf(x2 - m), e3 = __expf(x3 - m);
    float inv = 1.f / (e0 + e1 + e2 + e3);
    p_out[b * 4 + 0] = e0 * inv;
    p_out[b * 4 + 1] = e1 * inv;
    p_out[b * 4 + 2] = e2 * inv;
    p_out[b * 4 + 3] = e3 * inv;
    int idx = 0; float best = x0;                 // first-max, like jnp.argmax
    if (x1 > best) { best = x1; idx = 1; }
    if (x2 > best) { best = x2; idx = 2; }
    if (x3 > best) { best = x3; idx = 3; }
    kb[b] = (idx + 1) * (INNER_C / 4);
  }
}

// --- fp32 -> bf16 bulk convert, all 3 arrays in ONE launch ---------------
__global__ void cvt3_kernel(const float* __restrict__ h,
                            const float* __restrict__ w1,
                            const float* __restrict__ w2,
                            unsigned short* __restrict__ ha,
                            unsigned short* __restrict__ w1a,
                            unsigned short* __restrict__ w2a, int n8) {
  int i = blockIdx.x * blockDim.x + threadIdx.x;
  const float* in;
  unsigned short* out;
  int j;
  if (i < n8)          { in = h;  out = ha;  j = i; }
  else if (i < 2 * n8) { in = w1; out = w1a; j = i - n8; }
  else                 { in = w2; out = w2a; j = i - 2 * n8; }
  const float4* p = reinterpret_cast<const float4*>(in) + (size_t)j * 2;
  float4 a = p[0], b = p[1];
  u16x8 r;
  r[0] = f2bf(a.x); r[1] = f2bf(a.y); r[2] = f2bf(a.z); r[3] = f2bf(a.w);
  r[4] = f2bf(b.x); r[5] = f2bf(b.y); r[6] = f2bf(b.z); r[7] = f2bf(b.w);
  *(reinterpret_cast<u16x8*>(out) + j) = r;
}

// --- NT bf16 GEMM, 256x256, BK=32, 8 waves, 2-phase/K-tile, 2 blocks/CU --
// R13 with the launch_bounds spill fixed: hipcc treats the 2nd arg as
// BLOCKS/CU (CUDA semantics) -- arg=4 meant 32 waves/CU -> 64-VGPR cap ->
// acc (128 f32) spilled to scratch (R13: WRITE 7GB, MfmaUtil 3.4%).
// arg=2 -> 16 waves/CU -> 128-VGPR cap (R11-verified: VGPR=128, no spill).
// BK=32 keeps LDS at 64 KiB -> with VGPR=128, 2 blocks/CU co-resident;
// the second block feeds the LDS pipe during this block's LGK/BAR waits
// (R12 diagnosis: LDS-pipe-bound, pipe idles at reconvergence at 1 blk/CU).
// LDS per (buf, mat): [256 perm-rows][4 slots x 16B], slot XOR-swizzle
// slot' = slot ^ ((p>>1)&3) -> conflict-free b128 reads (verified: 0).
// Row perm (R5/R11-verified): A half0 = af-lo rows; B half0 = bf-lo rows.
// Stage unit = 1 gld_lds (128 perm-rows x 64B across 512 thr).
// Tile t (buf = t&1), stages target buf^1:
//  PA: rd af-lo(4)+bf-lo(2)+bf-hi(2); stage {B0,B1,A0}(t+1);
//      lgkm(4); bar; lgkm(0); MFMA Q1[0-3][0-1] Q2[0-3][2-3]; vmcnt(3); bar
//  PB: rd af-hi(4, overwrites af); stage {A1}(t+1);
//      bar; lgkm(0); MFMA Q3[4-7][2-3] Q4[4-7][0-1]; vmcnt(1); bar
// vmcnt FIFO (1 load/unit): end-PA(t) out = {A1(t), B0,B1,A0(t+1)} = 4 ->
// vmcnt(3) drains A1(t) [read in PB(t)]. end-PB(t) out = {B0,B1,A0,A1}(t+1)
// = 4 -> vmcnt(1) drains B0,B1,A0(t+1) [read PA(t+1), 1.5-2 phase cover].
// MODE 0: C = gelu(A*B^T + bias) -> bf16 H, skip col tiles >= kb[batch]
// MODE 1: C = A*B^T + bias -> f32 out, K-loop truncated to kb[batch]
template <int MODE>
__global__ __launch_bounds__(512, 2) void gemm_bt(
    const unsigned short* __restrict__ A,
    const unsigned short* __restrict__ Bp,
    const float* __restrict__ bias,
    void* __restrict__ Cp,
    const int* __restrict__ kb_arr) {
  constexpr int KDIM = (MODE == 0) ? DIM_C : INNER_C;   // A/B row stride
  __shared__ __align__(16) unsigned short sm[32768];    // 64 KiB

  const int nt = blockIdx.x;                            // col tile fastest
  const int mt = blockIdx.y;
  const size_t row0 = (size_t)mt * BM;
  const size_t col0 = (size_t)nt * BN;
  const int batch = (int)(row0 >> 11);                  // 2048 rows / batch
  const int kbv = kb_arr[batch];
  if (MODE == 0 && (int)col0 >= kbv) return;            // masked cols: skip
  const int kTiles = (MODE == 0) ? (DIM_C / BK) : (kbv / BK);  // even, >=64

  const int tid  = threadIdx.x;
  const int wave = tid >> 6;
  const int lane = tid & 63;
  const int wm = wave >> 2, wn = wave & 3;              // 2x4 wave grid
  const int la = lane & 15, lb4 = lane >> 4;

  // staging bases (permuted-row order; per-wave 16 contiguous global rows)
  const int sslot = ((lane & 3) ^ ((lane >> 3) & 3)) * 8;
  const unsigned short* gA =
      A + (row0 + (size_t)((wave >> 2) * 128 + (wave & 3) * 16 + (lane >> 2)))
              * KDIM + sslot;
  const unsigned short* gB =
      Bp + (col0 + (size_t)((wave >> 1) * 64 + (wave & 1) * 16 + (lane >> 2)))
               * KDIM + sslot;

  // STAGE: one unit = 128 perm-rows x 64B = 1 gld_lds/thread.
  // matofs: A=0, B=8192. HROWS: A=64, B=32 (global rows per unit-half).
#define STAGE(gp, matofs, BUF, H, T, HROWS)                                   \
  {                                                                           \
    const unsigned short* g_ = gp + (size_t)(H) * (HROWS) * KDIM + (T) * 32;  \
    gld_lds16(g_, &sm[(BUF) * 16384 + (matofs) + (H) * 4096 + wave * 512]);   \
  }

#define VMW_(N) asm volatile("s_waitcnt vmcnt(" #N ")" ::: "memory")
#define VMW(N) VMW_(N)
#define LGK_(N) asm volatile("s_waitcnt lgkmcnt(" #N ")" ::: "memory")
#define LGK(N) LGK_(N)
#define BAR __builtin_amdgcn_s_barrier()

  // frag read bases (ushort units); perm row p, stride 32, swizzled slot.
  const int rslot = (lb4 ^ ((la >> 1) & 3)) * 8;
  const int aro = (wm * 64 + la) * 32 + rslot;          // af-lo p-base
  const int bro = 8192 + (wn * 32 + la) * 32 + rslot;   // bf-lo p-base

  f32x4 acc[8][4];
#pragma unroll
  for (int m = 0; m < 8; ++m)
#pragma unroll
    for (int n = 0; n < 4; ++n) acc[m][n] = (f32x4){0.f, 0.f, 0.f, 0.f};

  bf16x8 af[4], bf[2], bf2[2];

#define RD_AF(BUF, HI)                                                        \
  _Pragma("unroll") for (int m_ = 0; m_ < 4; ++m_)                            \
      af[m_] = *reinterpret_cast<const bf16x8*>(                              \
          &sm[(BUF) * 16384 + aro + (HI) * 4096 + m_ * 512]);

#define RD_BF(DST, BUF, HI)                                                   \
  _Pragma("unroll") for (int n_ = 0; n_ < 2; ++n_)                            \
      DST[n_] = *reinterpret_cast<const bf16x8*>(                             \
          &sm[(BUF) * 16384 + bro + (HI) * 4096 + n_ * 512]);

#define MFMA_Q(AF, BF, MO, NO)                                                \
  __builtin_amdgcn_s_setprio(1);                                              \
  _Pragma("unroll") for (int m_ = 0; m_ < 4; ++m_)                            \
      _Pragma("unroll") for (int n_ = 0; n_ < 2; ++n_)                        \
          acc[(MO) + m_][(NO) + n_] =                                         \
              __builtin_amdgcn_mfma_f32_16x16x32_bf16(                        \
                  AF[m_], BF[n_], acc[(MO) + m_][(NO) + n_], 0, 0, 0);        \
  __builtin_amdgcn_s_setprio(0);

  // prologue: stage tile0 units in ledger order {B0,B1,A0 | A1}
  STAGE(gB, 8192, 0, 0, 0, 32);
  STAGE(gB, 8192, 0, 1, 0, 32);
  STAGE(gA, 0,    0, 0, 0, 64);
  STAGE(gA, 0,    0, 1, 0, 64);
  VMW(1);                                   // B0,B1,A0 landed; A1 in flight
  BAR;

#define TILE_S(T, BUF)                                                        \
  { /* PA */                                                                  \
    RD_AF(BUF, 0) RD_BF(bf, BUF, 0) RD_BF(bf2, BUF, 1)                        \
    STAGE(gB, 8192, (BUF) ^ 1, 0, (T) + 1, 32);                               \
    STAGE(gB, 8192, (BUF) ^ 1, 1, (T) + 1, 32);                               \
    STAGE(gA, 0,    (BUF) ^ 1, 0, (T) + 1, 64);                               \
    LGK(4); BAR; LGK(0);                                                      \
    MFMA_Q(af, bf, 0, 0)                                                      \
    MFMA_Q(af, bf2, 0, 2)                                                     \
    VMW(3); BAR;                                                              \
    /* PB */                                                                  \
    RD_AF(BUF, 1)                                                             \
    STAGE(gA, 0, (BUF) ^ 1, 1, (T) + 1, 64);                                  \
    BAR; LGK(0);                                                              \
    MFMA_Q(af, bf2, 4, 2)                                                     \
    MFMA_Q(af, bf, 4, 0)                                                      \
    VMW(1); BAR;                                                              \
  }

#define TILE_LAST(BUF)                                                        \
  { /* PA */                                                                  \
    RD_AF(BUF, 0) RD_BF(bf, BUF, 0) RD_BF(bf2, BUF, 1)                        \
    LGK(4); BAR; LGK(0);                                                      \
    MFMA_Q(af, bf, 0, 0)                                                      \
    MFMA_Q(af, bf2, 0, 2)                                                     \
    VMW(0); BAR;                                                              \
    /* PB */                                                                  \
    RD_AF(BUF, 1)                                                             \
    LGK(0);                                                                   \
    MFMA_Q(af, bf2, 4, 2)                                                     \
    MFMA_Q(af, bf, 4, 0)                                                      \
  }

  for (int t = 0; t + 2 < kTiles; t += 2) {
    TILE_S(t, 0);
    TILE_S(t + 1, 1);
  }
  TILE_S(kTiles - 2, 0);
  TILE_LAST(1);

#undef TILE_S
#undef TILE_LAST
#undef MFMA_Q
#undef RD_AF
#undef RD_BF
#undef STAGE

  // epilogue: C/D layout col = lane&15, row = (lane>>4)*4 + j  [m89/m91]
#pragma unroll
  for (int m = 0; m < 8; ++m) {
    const size_t rb = row0 + wm * 128 + m * 16 + lb4 * 4;
#pragma unroll
    for (int n = 0; n < 4; ++n) {
      const size_t c = col0 + wn * 64 + n * 16 + la;
      const float bv = bias[c];
#pragma unroll
      for (int j = 0; j < 4; ++j) {
        float x = acc[m][n][j] + bv;
        if (MODE == 0) {
          float g = x / (1.f + __expf(-1.702f * x));  // x*sigmoid(1.702x)
          ((unsigned short*)Cp)[(rb + j) * (size_t)INNER_C + c] = f2bf(g);
        } else {
          ((float*)Cp)[(rb + j) * (size_t)DIM_C + c] = x;
        }
      }
    }
  }
}

extern "C" void kernel_launch(void* const* d_in, const int* in_sizes, int n_in,
                              void* d_out, int out_size, void* d_ws,
                              size_t ws_size, hipStream_t stream) {
  const float* hidden = (const float*)d_in[0];  // [4,2048,2048]
  const float* logitw = (const float*)d_in[1];  // [4,4]
  const float* W1     = (const float*)d_in[2];  // [8192,2048]
  const float* b1     = (const float*)d_in[3];  // [8192]
  const float* W2     = (const float*)d_in[4];  // [2048,8192]
  const float* b2     = (const float*)d_in[5];  // [2048]
  float* out   = (float*)d_out;
  float* p_out = out + (size_t)ROWS * DIM_C;    // tuple tail: p_soft [4,4]

  char* ws = (char*)d_ws;
  int*            kb   = (int*)ws;                                    // 16 B
  unsigned short* Abf  = (unsigned short*)(ws + 256);                 // 32 MiB
  unsigned short* W1bf = (unsigned short*)(ws + 256 + 33554432);      // 32 MiB
  unsigned short* W2bf = (unsigned short*)(ws + 256 + 2 * 33554432);  // 32 MiB
  unsigned short* Hbf  = (unsigned short*)(ws + 256 + 3 * 33554432);  // 128 MiB

  prep_kernel<<<1, 64, 0, stream>>>(logitw, p_out, kb);

  const int n8 = 16777216 / 8;  // each of A/W1/W2 is 16.7M fp32
  cvt3_kernel<<<3 * n8 / 256, 256, 0, stream>>>(hidden, W1, W2, Abf, W1bf,
                                                W2bf, n8);

  gemm_bt<0><<<dim3(INNER_C / BN, ROWS / BM), 512, 0, stream>>>(
      Abf, W1bf, b1, Hbf, kb);
  gemm_bt<1><<<dim3(DIM_C / BN, ROWS / BM), 512, 0, stream>>>(
      Hbf, W2bf, b2, out, kb);
}

// Round 15
// 459.718 us; speedup vs baseline: 11.2150x; 1.1763x over previous
//
#include <hip/hip_runtime.h>
#include <stdint.h>

#define DIM_C   2048
#define INNER_C 8192
#define ROWS    8192      // B*L = 4*2048
#define BM 256
#define BN 256
#define BK 64

using bf16x8 = __attribute__((ext_vector_type(8))) __bf16;
using f32x4  = __attribute__((ext_vector_type(4))) float;
using u16x8  = __attribute__((ext_vector_type(8))) unsigned short;

__device__ __forceinline__ unsigned short f2bf(float f) {
  union { float f; unsigned int u; } v; v.f = f;
  unsigned int u = v.u;
  return (unsigned short)((u + 0x7FFFu + ((u >> 16) & 1u)) >> 16);  // RTNE
}

__device__ __forceinline__ void gld_lds16(const void* g, void* l) {
  __builtin_amdgcn_global_load_lds(
      (__attribute__((address_space(1))) void*)(g),
      (__attribute__((address_space(3))) void*)(l), 16, 0, 0);
}

// --- softmax + per-batch truncation width --------------------------------
__global__ void prep_kernel(const float* __restrict__ logits,
                            float* __restrict__ p_out,
                            int* __restrict__ kb) {
  const int b = threadIdx.x;
  if (b < 4) {
    float x0 = logits[b * 4 + 0], x1 = logits[b * 4 + 1];
    float x2 = logits[b * 4 + 2], x3 = logits[b * 4 + 3];
    float m = fmaxf(fmaxf(x0, x1), fmaxf(x2, x3));
    float e0 = __expf(x0 - m), e1 = __expf(x1 - m);
    float e2 = __expf(x2 - m), e3 = __expf(x3 - m);
    float inv = 1.f / (e0 + e1 + e2 + e3);
    p_out[b * 4 + 0] = e0 * inv;
    p_out[b * 4 + 1] = e1 * inv;
    p_out[b * 4 + 2] = e2 * inv;
    p_out[b * 4 + 3] = e3 * inv;
    int idx = 0; float best = x0;                 // first-max, like jnp.argmax
    if (x1 > best) { best = x1; idx = 1; }
    if (x2 > best) { best = x2; idx = 2; }
    if (x3 > best) { best = x3; idx = 3; }
    kb[b] = (idx + 1) * (INNER_C / 4);
  }
}

// --- fp32 -> bf16 bulk convert, all 3 arrays in ONE launch ---------------
__global__ void cvt3_kernel(const float* __restrict__ h,
                            const float* __restrict__ w1,
                            const float* __restrict__ w2,
                            unsigned short* __restrict__ ha,
                            unsigned short* __restrict__ w1a,
                            unsigned short* __restrict__ w2a, int n8) {
  int i = blockIdx.x * blockDim.x + threadIdx.x;
  const float* in;
  unsigned short* out;
  int j;
  if (i < n8)          { in = h;  out = ha;  j = i; }
  else if (i < 2 * n8) { in = w1; out = w1a; j = i - n8; }
  else                 { in = w2; out = w2a; j = i - 2 * n8; }
  const float4* p = reinterpret_cast<const float4*>(in) + (size_t)j * 2;
  float4 a = p[0], b = p[1];
  u16x8 r;
  r[0] = f2bf(a.x); r[1] = f2bf(a.y); r[2] = f2bf(a.z); r[3] = f2bf(a.w);
  r[4] = f2bf(b.x); r[5] = f2bf(b.y); r[6] = f2bf(b.z); r[7] = f2bf(b.w);
  *(reinterpret_cast<u16x8*>(out) + j) = r;
}

// --- NT bf16 GEMM, 256x256, BK=64, 8 waves, 4-phase/K-tile ---------------
// R11 champion (482us wall) with the redundant mid-phase sync removed:
// each phase was "reads; LGK(8); BAR; LGK(0); MFMA" -- the full lgkm drain
// + extra barrier serialized ~150cyc of LDS latency onto every phase, yet
// protects nothing (reads hit buf, stable all tile; DMA stages hit buf^1,
// quiescent all tile). Now "reads; stage; MFMA": the compiler emits
// counted lgkmcnt(N) per MFMA use (m97-verified), so MFMAs on early frags
// issue while later reads are in flight. Barriers 8->4/tile; trailing
// per-phase barrier kept (lockstep = L2 burst locality, R6 lesson);
// vmcnt ledger unchanged (R5/R11-verified).
// Plain 2D grid (nt fastest; R11-verified L2 fit: FETCH 388->204MB).
// LDS per (buf, mat): [kh 2][256 perm-rows][4 slots x 16B], slot XOR-swz
// slot' = slot ^ ((p>>1)&3) -> conflict-free b128 reads (verified: 0).
// Row perm halves: A half0 = af-lo rows; B half0 = bf-lo (R5 mapping).
// Phases of tile t (buf = t&1), stages target buf^1 (quiescent):
//   P1: rd af-lo(8)+bf-lo(4); stage (t+1,B-lo); MFMA [0-3][0-1]; vmcnt(4)
//   P2: rd bf-hi(4);          stage (t+1,A-lo); MFMA [0-3][2-3]; vmcnt(4)
//   P3: rd af-hi(8, overwrites af); stage (t+1,B-hi); MFMA [4-7][2-3]
//   P4:                       stage (t+1,A-hi); MFMA [4-7][0-1]; vmcnt(4)
// vmcnt FIFO: end-P1 drains Bhi(t) [P2 reads]; end-P2 drains Ahi(t)
// [P3 reads]; end-P4 drains Blo,Alo(t+1) [P1(t+1) reads]. All counted.
// MODE 0: C = gelu(A*B^T + bias) -> bf16 H, skip col tiles >= kb[batch]
// MODE 1: C = A*B^T + bias -> f32 out, K-loop truncated to kb[batch]
template <int MODE>
__global__ __launch_bounds__(512, 2) void gemm_bt(
    const unsigned short* __restrict__ A,
    const unsigned short* __restrict__ Bp,
    const float* __restrict__ bias,
    void* __restrict__ Cp,
    const int* __restrict__ kb_arr) {
  constexpr int KDIM = (MODE == 0) ? DIM_C : INNER_C;   // A/B row stride
  __shared__ __align__(16) unsigned short sm[65536];    // 128 KiB

  const int nt = blockIdx.x;                            // col tile fastest
  const int mt = blockIdx.y;
  const size_t row0 = (size_t)mt * BM;
  const size_t col0 = (size_t)nt * BN;
  const int batch = (int)(row0 >> 11);                  // 2048 rows / batch
  const int kbv = kb_arr[batch];
  if (MODE == 0 && (int)col0 >= kbv) return;            // masked cols: skip
  const int kTiles = (MODE == 0) ? (DIM_C / BK) : (kbv / BK);  // even, >=32

  const int tid  = threadIdx.x;
  const int wave = tid >> 6;
  const int lane = tid & 63;
  const int wm = wave >> 2, wn = wave & 3;              // 2x4 wave grid
  const int la = lane & 15, lb4 = lane >> 4;

  // staging bases (permuted-row order; per-wave 16 contiguous global rows)
  const int sslot = ((lane & 3) ^ ((lane >> 3) & 3)) * 8;
  const unsigned short* gA =
      A + (row0 + (size_t)((wave >> 2) * 128 + (wave & 3) * 16 + (lane >> 2)))
              * KDIM + sslot;
  const unsigned short* gB =
      Bp + (col0 + (size_t)((wave >> 1) * 64 + (wave & 1) * 16 + (lane >> 2)))
               * KDIM + sslot;

  // STAGE: one half-tile (2 x gld_lds, one per kh). HROWS: A=64, B=32.
#define STAGE(gp, matofs, BUF, H, T, HROWS)                                   \
  {                                                                           \
    const unsigned short* g_ = gp + (size_t)(H) * (HROWS) * KDIM + (T) * 64;  \
    gld_lds16(g_, &sm[(BUF) * 32768 + (matofs) + (H) * 4096 + wave * 512]);   \
    gld_lds16(g_ + 32,                                                        \
              &sm[(BUF) * 32768 + (matofs) + 8192 + (H) * 4096 + wave * 512]);\
  }

#define VMW_(N) asm volatile("s_waitcnt vmcnt(" #N ")" ::: "memory")
#define VMW(N) VMW_(N)
#define BAR __builtin_amdgcn_s_barrier()

  // frag read bases (ushort units); permuted row p, stride 32, swz slot.
  const int rslot = (lb4 ^ ((la >> 1) & 3)) * 8;
  const int aro = (wm * 64 + la) * 32 + rslot;          // af-lo p-base
  const int bro = 16384 + (wn * 32 + la) * 32 + rslot;  // bf-lo p-base

  f32x4 acc[8][4];
#pragma unroll
  for (int m = 0; m < 8; ++m)
#pragma unroll
    for (int n = 0; n < 4; ++n) acc[m][n] = (f32x4){0.f, 0.f, 0.f, 0.f};

  bf16x8 af[4][2], bf[2][2], bf2[2][2];

#define RD_AF(BUF, HI)                                                        \
  _Pragma("unroll") for (int m_ = 0; m_ < 4; ++m_)                            \
      _Pragma("unroll") for (int k_ = 0; k_ < 2; ++k_)                        \
          af[m_][k_] = *reinterpret_cast<const bf16x8*>(                      \
              &sm[(BUF) * 32768 + k_ * 8192 + aro + (HI) * 4096 + m_ * 512]);

#define RD_BF(DST, BUF, HI)                                                   \
  _Pragma("unroll") for (int n_ = 0; n_ < 2; ++n_)                            \
      _Pragma("unroll") for (int k_ = 0; k_ < 2; ++k_)                        \
          DST[n_][k_] = *reinterpret_cast<const bf16x8*>(                     \
              &sm[(BUF) * 32768 + k_ * 8192 + bro + (HI) * 4096 + n_ * 512]);

#define MFMA_Q(AF, BF, MO, NO)                                                \
  __builtin_amdgcn_s_setprio(1);                                              \
  _Pragma("unroll") for (int m_ = 0; m_ < 4; ++m_)                            \
      _Pragma("unroll") for (int n_ = 0; n_ < 2; ++n_)                        \
          _Pragma("unroll") for (int k_ = 0; k_ < 2; ++k_)                    \
              acc[(MO) + m_][(NO) + n_] =                                     \
                  __builtin_amdgcn_mfma_f32_16x16x32_bf16(                    \
                      AF[m_][k_], BF[n_][k_], acc[(MO) + m_][(NO) + n_],      \
                      0, 0, 0);                                               \
  __builtin_amdgcn_s_setprio(0);

  // prologue: stage tile0's 4 halves (FIFO: Blo, Alo, Bhi, Ahi)
  STAGE(gB, 16384, 0, 0, 0, 32);
  STAGE(gA, 0,     0, 0, 0, 64);
  STAGE(gB, 16384, 0, 1, 0, 32);
  STAGE(gA, 0,     0, 1, 0, 64);
  VMW(4);                                   // Blo, Alo landed
  BAR;

#define TILE_S(T, BUF)                                                        \
  { /* P1 */                                                                  \
    RD_AF(BUF, 0) RD_BF(bf, BUF, 0)                                           \
    STAGE(gB, 16384, (BUF) ^ 1, 0, (T) + 1, 32);                              \
    MFMA_Q(af, bf, 0, 0)                                                      \
    VMW(4); BAR;                                                              \
    /* P2 */                                                                  \
    RD_BF(bf2, BUF, 1)                                                        \
    STAGE(gA, 0, (BUF) ^ 1, 0, (T) + 1, 64);                                  \
    MFMA_Q(af, bf2, 0, 2)                                                     \
    VMW(4); BAR;                                                              \
    /* P3 */                                                                  \
    RD_AF(BUF, 1)                                                             \
    STAGE(gB, 16384, (BUF) ^ 1, 1, (T) + 1, 32);                              \
    MFMA_Q(af, bf2, 4, 2)                                                     \
    BAR;                                                                      \
    /* P4 */                                                                  \
    STAGE(gA, 0, (BUF) ^ 1, 1, (T) + 1, 64);                                  \
    MFMA_Q(af, bf, 4, 0)                                                      \
    VMW(4); BAR;                                                              \
  }

#define TILE_T(BUF)                                                           \
  { /* P1 */                                                                  \
    RD_AF(BUF, 0) RD_BF(bf, BUF, 0)                                           \
    MFMA_Q(af, bf, 0, 0)                                                      \
    VMW(2); BAR;                                                              \
    /* P2 */                                                                  \
    RD_BF(bf2, BUF, 1)                                                        \
    MFMA_Q(af, bf2, 0, 2)                                                     \
    VMW(0); BAR;                                                              \
    /* P3 */                                                                  \
    RD_AF(BUF, 1)                                                             \
    MFMA_Q(af, bf2, 4, 2)                                                     \
    /* P4 (registers only) */                                                 \
    MFMA_Q(af, bf, 4, 0)                                                      \
  }

  for (int t = 0; t + 2 < kTiles; t += 2) {
    TILE_S(t, 0);
    TILE_S(t + 1, 1);
  }
  TILE_S(kTiles - 2, 0);
  TILE_T(1);

#undef TILE_S
#undef TILE_T
#undef MFMA_Q
#undef RD_AF
#undef RD_BF
#undef STAGE

  // epilogue: C/D layout col = lane&15, row = (lane>>4)*4 + j  [m89/m91]
#pragma unroll
  for (int m = 0; m < 8; ++m) {
    const size_t rb = row0 + wm * 128 + m * 16 + lb4 * 4;
#pragma unroll
    for (int n = 0; n < 4; ++n) {
      const size_t c = col0 + wn * 64 + n * 16 + la;
      const float bv = bias[c];
#pragma unroll
      for (int j = 0; j < 4; ++j) {
        float x = acc[m][n][j] + bv;
        if (MODE == 0) {
          float g = x / (1.f + __expf(-1.702f * x));  // x*sigmoid(1.702x)
          ((unsigned short*)Cp)[(rb + j) * (size_t)INNER_C + c] = f2bf(g);
        } else {
          ((float*)Cp)[(rb + j) * (size_t)DIM_C + c] = x;
        }
      }
    }
  }
}

extern "C" void kernel_launch(void* const* d_in, const int* in_sizes, int n_in,
                              void* d_out, int out_size, void* d_ws,
                              size_t ws_size, hipStream_t stream) {
  const float* hidden = (const float*)d_in[0];  // [4,2048,2048]
  const float* logitw = (const float*)d_in[1];  // [4,4]
  const float* W1     = (const float*)d_in[2];  // [8192,2048]
  const float* b1     = (const float*)d_in[3];  // [8192]
  const float* W2     = (const float*)d_in[4];  // [2048,8192]
  const float* b2     = (const float*)d_in[5];  // [2048]
  float* out   = (float*)d_out;
  float* p_out = out + (size_t)ROWS * DIM_C;    // tuple tail: p_soft [4,4]

  char* ws = (char*)d_ws;
  int*            kb   = (int*)ws;                                    // 16 B
  unsigned short* Abf  = (unsigned short*)(ws + 256);                 // 32 MiB
  unsigned short* W1bf = (unsigned short*)(ws + 256 + 33554432);      // 32 MiB
  unsigned short* W2bf = (unsigned short*)(ws + 256 + 2 * 33554432);  // 32 MiB
  unsigned short* Hbf  = (unsigned short*)(ws + 256 + 3 * 33554432);  // 128 MiB

  prep_kernel<<<1, 64, 0, stream>>>(logitw, p_out, kb);

  const int n8 = 16777216 / 8;  // each of A/W1/W2 is 16.7M fp32
  cvt3_kernel<<<3 * n8 / 256, 256, 0, stream>>>(hidden, W1, W2, Abf, W1bf,
                                                W2bf, n8);

  gemm_bt<0><<<dim3(INNER_C / BN, ROWS / BM), 512, 0, stream>>>(
      Abf, W1bf, b1, Hbf, kb);
  gemm_bt<1><<<dim3(DIM_C / BN, ROWS / BM), 512, 0, stream>>>(
      Hbf, W2bf, b2, out, kb);
}